// Round 4
// baseline (273.663 us; speedup 1.0000x reference)
//
#include <hip/hip_runtime.h>
#include <math.h>

#define BATCHES 8192
#define D_IN    400
#define D_OUT   100
#define QD      10
#define KT      64
#define NKT     7                              // 7*64 = 448 >= 400
#define MTILES  7                              // 7*16 = 112 >= 100
#define WFSZ    (NKT * MTILES * 2 * 64 * 8)    // 50176 shorts per plane
#define XB      648                            // floats per batch region (640 + 8 pad)
#define NW      4                              // waves per block, 2 batches per wave
#define WCH     512                            // shorts per W chunk (64 lanes x 8)
#define WHALF   (14 * WCH)                     // 7168 shorts: one (kt,ks) half-tile, both planes

using bf16x8 = __attribute__((ext_vector_type(8))) short;
using f32x4  = __attribute__((ext_vector_type(4))) float;

// ---- wave-64 sum via DPP (row_shr + row_bcast), result broadcast via SGPR ----
template <int CTRL>
__device__ __forceinline__ float dpp_add(float x) {
  int s = __builtin_amdgcn_update_dpp(0, __builtin_bit_cast(int, x),
                                      CTRL, 0xF, 0xF, true);
  return x + __builtin_bit_cast(float, s);
}

__device__ __forceinline__ float wsum64(float x) {
  x = dpp_add<0x111>(x);   // row_shr:1
  x = dpp_add<0x112>(x);   // row_shr:2
  x = dpp_add<0x114>(x);   // row_shr:4
  x = dpp_add<0x118>(x);   // row_shr:8
  x = dpp_add<0x142>(x);   // row_bcast:15
  x = dpp_add<0x143>(x);   // row_bcast:31 -> lane63 has total
  return __builtin_bit_cast(float,
      __builtin_amdgcn_readlane(__builtin_bit_cast(int, x), 63));
}

__device__ __forceinline__ float lane_bcast(float x, int lane) {
  return __builtin_bit_cast(float,
      __builtin_amdgcn_readlane(__builtin_bit_cast(int, x), lane));
}

// barrier that does NOT drain vmcnt (keeps X/W prefetches in flight).
__device__ __forceinline__ void lds_barrier() {
  asm volatile("s_waitcnt lgkmcnt(0)" ::: "memory");
  __builtin_amdgcn_s_barrier();
  __builtin_amdgcn_sched_barrier(0);
}

// ---------- prep: W (100,400) fp32 -> A-fragment-ordered bf16 hi/lo planes ----
// layout: e = (((kt*7+mt)*2+ks)*64 + lane)*8 + j ; lane = quad*16 + row16
__global__ __launch_bounds__(256) void wprep_kernel(const float* __restrict__ W,
                                                    short* __restrict__ wfh,
                                                    short* __restrict__ wfl) {
  const int e = blockIdx.x * 256 + threadIdx.x;
  if (e >= WFSZ) return;
  const int j = e & 7, lane = (e >> 3) & 63, ks = (e >> 9) & 1, mtkt = e >> 10;
  const int kt = mtkt / MTILES, mt = mtkt - kt * MTILES;
  const int o = mt * 16 + (lane & 15);
  const int k = kt * KT + ks * 32 + (lane >> 4) * 8 + j;
  const float w = (o < D_OUT && k < D_IN) ? W[o * D_IN + k] : 0.f;
  __bf16 h = (__bf16)w;
  float hf = (float)h;
  __bf16 l = (__bf16)(w - hf);
  wfh[e] = __builtin_bit_cast(short, h);
  wfl[e] = __builtin_bit_cast(short, l);
}

// ---------- QR (LAPACK sgeqrf convention), rcp-based, wave-private ----------
__device__ __forceinline__ void qr_and_store(const f32x4* acc, float* stg,
                                             float* dst, int lane, int col,
                                             int quad) {
  if (col < QD) {
    #pragma unroll
    for (int mt = 0; mt < MTILES; ++mt)
      #pragma unroll
      for (int rr = 0; rr < 4; ++rr) {
        const int o = mt * 16 + quad * 4 + rr;
        if (o < D_OUT) stg[o * QD + col] = acc[mt][rr];
      }
  }
  const int r = lane;
  float a0[QD], a1[QD];
  #pragma unroll
  for (int q = 0; q < QD; ++q) a0[q] = stg[r * QD + q];
  const bool has1 = (r + 64) < D_OUT;
  #pragma unroll
  for (int q = 0; q < QD; ++q) a1[q] = has1 ? stg[(r + 64) * QD + q] : 0.f;

  float v0[QD], v1[QD], tau[QD];
  #pragma unroll
  for (int j = 0; j < QD; ++j) {
    float cj0  = (r >= j) ? a0[j] : 0.f;
    float part = cj0 * cj0 + a1[j] * a1[j];
    float sig  = wsum64(part);
    float alpha = lane_bcast(a0[j], j);
    float nrm  = __builtin_amdgcn_sqrtf(sig);
    float aab  = fabsf(alpha);
    float rn   = __builtin_amdgcn_rcpf(nrm);
    float rd   = __builtin_amdgcn_rcpf(aab + nrm);
    float sgn  = (alpha >= 0.f) ? 1.f : -1.f;
    float tj   = (sig > 0.f) ? (1.f + aab * rn) : 0.f;
    float inv  = (sig > 0.f) ? sgn * rd : 0.f;      // 1/(alpha - beta)
    tau[j] = tj;
    v0[j]  = (r == j) ? 1.f : ((r > j) ? a0[j] * inv : 0.f);
    v1[j]  = a1[j] * inv;
    #pragma unroll
    for (int k = j + 1; k < QD; ++k) {
      float p = v0[j] * a0[k] + v1[j] * a1[k];
      float s = wsum64(p) * tj;
      a0[k] -= s * v0[j];
      a1[k] -= s * v1[j];
    }
  }
  float q0[QD], q1[QD];
  #pragma unroll
  for (int c = 0; c < QD; ++c) { q0[c] = (r == c) ? 1.f : 0.f; q1[c] = 0.f; }
  #pragma unroll
  for (int j = QD - 1; j >= 0; --j) {
    #pragma unroll
    for (int c = j; c < QD; ++c) {
      float p = v0[j] * q0[c] + v1[j] * q1[c];
      float s = wsum64(p) * tau[j];
      q0[c] -= s * v0[j];
      q1[c] -= s * v1[j];
    }
  }
  #pragma unroll
  for (int c = 0; c < QD; ++c) stg[r * QD + c] = q0[c];
  if (has1) {
    #pragma unroll
    for (int c = 0; c < QD; ++c) stg[(r + 64) * QD + c] = q1[c];
  }
  const float4* src = (const float4*)stg;
  float4* d4 = (float4*)dst;
  #pragma unroll
  for (int u = r; u < (D_OUT * QD) / 4; u += 64) d4[u] = src[u];
}

// ---------- fused: Y = W@X[b] (MFMA, W half-tiles staged in LDS) + QR -------
__global__ __launch_bounds__(256, 4) void fused_kernel(const float* __restrict__ X,
                                                       const short* __restrict__ wfh,
                                                       const short* __restrict__ wfl,
                                                       float* __restrict__ out) {
  __shared__ __align__(16) float xstg[NW * 2 * XB];   // 20736 B wave-private X / QR stg
  __shared__ __align__(16) short wtile[WHALF];        // 14336 B block-shared W half-tile
  const int tid  = threadIdx.x;
  const int lane = tid & 63;
  const int wv   = __builtin_amdgcn_readfirstlane(tid >> 6);
  const long b0  = (long)blockIdx.x * (NW * 2) + wv * 2;
  float* xs = xstg + wv * (2 * XB);
  const int col = lane & 15, quad = lane >> 4;

  f32x4 acc0[MTILES], acc1[MTILES];
  #pragma unroll
  for (int t = 0; t < MTILES; ++t) {
    acc0[t] = (f32x4){0.f, 0.f, 0.f, 0.f};
    acc1[t] = (f32x4){0.f, 0.f, 0.f, 0.f};
  }

  // W half-tile staging: chunks c = wv, wv+4, wv+8, wv+12 (c<14).
  // chunk c: plane = c/7 (0=hi,1=lo), mt = c%7 ; LDS offset = c*WCH + lane*8.
  bf16x8 wst[4];
  auto wload = [&](int kt, int ks) {
    #pragma unroll
    for (int i = 0; i < 4; ++i) {
      const int c = wv + 4 * i;
      if (c < 14) {
        const short* pl = (c < 7) ? wfh : wfl;
        const int m = (c < 7) ? c : c - 7;
        wst[i] = *(const bf16x8*)(pl + ((long)(kt * 7 + m) * 2 + ks) * WCH + lane * 8);
      }
    }
  };
  auto wcommit = [&]() {
    #pragma unroll
    for (int i = 0; i < 4; ++i) {
      const int c = wv + 4 * i;
      if (c < 14) *(bf16x8*)&wtile[c * WCH + lane * 8] = wst[i];
    }
  };

  // X register prefetch (2 batches, 160 float4 each -> 5 per lane)
  float4 pre[5];
  auto xpre = [&](int kt) {
    const int nk0 = kt * KT;
    const int vf4 = (nk0 + KT <= D_IN) ? 160 : ((D_IN - nk0) * QD) / 4;  // 160 | 40
    #pragma unroll
    for (int u = 0; u < 5; ++u) {
      const int idx = lane + u * 64;
      const int bsel = idx >= 160 ? 1 : 0;
      const int within = idx - bsel * 160;
      float4 v = {0.f, 0.f, 0.f, 0.f};
      if (within < vf4)
        v = *(const float4*)(X + (b0 + bsel) * (long)(D_IN * QD) + nk0 * QD + within * 4);
      pre[u] = v;
    }
  };
  auto xcommit = [&]() {
    #pragma unroll
    for (int u = 0; u < 5; ++u) {
      const int idx = lane + u * 64;
      const int bsel = idx >= 160 ? 1 : 0;
      const int within = idx - bsel * 160;
      *(float4*)&xs[bsel * XB + within * 4] = pre[u];
    }
  };

  // one (kt,ks) half-tile of MFMA work for both batches
  auto computeHalf = [&](int ks) {
    bf16x8 b0h, b0l, b1h, b1l;
    #pragma unroll
    for (int m = 0; m < 8; ++m) {
      const int fo = (ks * 32 + quad * 8 + m) * QD + col;
      float x0 = xs[fo];
      float x1 = xs[XB + fo];
      __bf16 h0 = (__bf16)x0; float f0 = (float)h0; __bf16 g0 = (__bf16)(x0 - f0);
      __bf16 h1 = (__bf16)x1; float f1 = (float)h1; __bf16 g1 = (__bf16)(x1 - f1);
      b0h[m] = __builtin_bit_cast(short, h0); b0l[m] = __builtin_bit_cast(short, g0);
      b1h[m] = __builtin_bit_cast(short, h1); b1l[m] = __builtin_bit_cast(short, g1);
    }
    #pragma unroll
    for (int mt = 0; mt < MTILES; ++mt) {
      bf16x8 ah = *(const bf16x8*)&wtile[mt * WCH + lane * 8];
      bf16x8 al = *(const bf16x8*)&wtile[(7 + mt) * WCH + lane * 8];
      acc0[mt] = __builtin_amdgcn_mfma_f32_16x16x32_bf16(ah, b0h, acc0[mt], 0, 0, 0);
      acc0[mt] = __builtin_amdgcn_mfma_f32_16x16x32_bf16(al, b0h, acc0[mt], 0, 0, 0);
      acc0[mt] = __builtin_amdgcn_mfma_f32_16x16x32_bf16(ah, b0l, acc0[mt], 0, 0, 0);
      acc1[mt] = __builtin_amdgcn_mfma_f32_16x16x32_bf16(ah, b1h, acc1[mt], 0, 0, 0);
      acc1[mt] = __builtin_amdgcn_mfma_f32_16x16x32_bf16(al, b1h, acc1[mt], 0, 0, 0);
      acc1[mt] = __builtin_amdgcn_mfma_f32_16x16x32_bf16(ah, b1l, acc1[mt], 0, 0, 0);
    }
  };

  // ---- prologue: W(0,0) -> LDS, X(0) -> regs ----
  wload(0, 0);
  xpre(0);
  wcommit();          // compiler waits vmcnt for wst regs only (X stays in flight)
  lds_barrier();

  #pragma unroll 1
  for (int kt = 0; kt < NKT; ++kt) {
    // ---- phase ks=0 (wtile holds (kt,0)) ----
    wload(kt, 1);                    // next half -> regs (in flight during compute)
    xcommit();                       // X(kt) regs -> LDS (wave-private)
    if (kt + 1 < NKT) xpre(kt + 1);  // X(kt+1) -> regs (in flight across phases)
    computeHalf(0);
    lds_barrier();                   // everyone done reading (kt,0)
    wcommit();                       // write (kt,1)
    lds_barrier();                   // (kt,1) visible
    // ---- phase ks=1 (wtile holds (kt,1)) ----
    if (kt + 1 < NKT) wload(kt + 1, 0);
    computeHalf(1);
    lds_barrier();                   // everyone done reading (kt,1)
    if (kt + 1 < NKT) wcommit();     // write (kt+1,0)
    lds_barrier();
  }

  // ---- fused QR + store (stg reuses the X region; wave-private, no barriers) ----
  qr_and_store(acc0, xs, out + b0 * (long)(D_OUT * QD), lane, col, quad);
  qr_and_store(acc1, xs, out + (b0 + 1) * (long)(D_OUT * QD), lane, col, quad);
}

extern "C" void kernel_launch(void* const* d_in, const int* in_sizes, int n_in,
                              void* d_out, int out_size, void* d_ws, size_t ws_size,
                              hipStream_t stream) {
  const float* X = (const float*)d_in[0];   // (8192, 400, 10) fp32
  const float* W = (const float*)d_in[1];   // (100, 400) fp32
  float* out = (float*)d_out;               // (8192, 100, 10) fp32
  short* wfh = (short*)d_ws;                // 50176 shorts
  short* wfl = wfh + WFSZ;                  // 50176 shorts
  hipLaunchKernelGGL(wprep_kernel, dim3((WFSZ + 255) / 256), dim3(256), 0, stream,
                     W, wfh, wfl);
  hipLaunchKernelGGL(fused_kernel, dim3(BATCHES / (NW * 2)), dim3(256), 0, stream,
                     X, wfh, wfl, out);
}

// Round 5
// 220.828 us; speedup vs baseline: 1.2393x; 1.2393x over previous
//
#include <hip/hip_runtime.h>
#include <math.h>

#define BATCHES 8192
#define D_IN    400
#define D_OUT   100
#define QD      10
#define KT      64
#define NKT     7                              // 7*64 = 448 >= 400
#define MTILES  7                              // 7*16 = 112 >= 100
#define WFSZ    (NKT * MTILES * 2 * 64 * 8)    // 50176 shorts per plane
#define XB      648                            // floats per batch region (640 + 8 pad)
#define NW      4                              // waves per block, 2 batches per wave
#define WCH     512                            // shorts per W chunk (64 lanes x 8)
#define WHALF   (14 * WCH)                     // shorts per (kt,ks) half-tile (hi+lo planes)

using bf16x8 = __attribute__((ext_vector_type(8))) short;
using f32x4  = __attribute__((ext_vector_type(4))) float;

// ---- wave-64 sum via DPP (row_shr + row_bcast), result broadcast via SGPR ----
template <int CTRL>
__device__ __forceinline__ float dpp_add(float x) {
  int s = __builtin_amdgcn_update_dpp(0, __builtin_bit_cast(int, x),
                                      CTRL, 0xF, 0xF, true);
  return x + __builtin_bit_cast(float, s);
}

__device__ __forceinline__ float wsum64(float x) {
  x = dpp_add<0x111>(x);   // row_shr:1
  x = dpp_add<0x112>(x);   // row_shr:2
  x = dpp_add<0x114>(x);   // row_shr:4
  x = dpp_add<0x118>(x);   // row_shr:8
  x = dpp_add<0x142>(x);   // row_bcast:15
  x = dpp_add<0x143>(x);   // row_bcast:31 -> lane63 has total
  return __builtin_bit_cast(float,
      __builtin_amdgcn_readlane(__builtin_bit_cast(int, x), 63));
}

__device__ __forceinline__ float lane_bcast(float x, int lane) {
  return __builtin_bit_cast(float,
      __builtin_amdgcn_readlane(__builtin_bit_cast(int, x), lane));
}

// async global->LDS, 16B per lane: per-lane global src, wave-uniform LDS base
// (HW writes base + lane*16). Tracked by vmcnt.
__device__ __forceinline__ void gload_lds16(const short* g, short* l) {
  __builtin_amdgcn_global_load_lds(
      (const __attribute__((address_space(1))) void*)g,
      (__attribute__((address_space(3))) void*)l, 16, 0, 0);
}

// ---------- prep: W (100,400) fp32 -> A-fragment-ordered bf16 hi/lo planes ----
// layout: e = (((kt*7+mt)*2+ks)*64 + lane)*8 + j ; lane = quad*16 + row16
__global__ __launch_bounds__(256) void wprep_kernel(const float* __restrict__ W,
                                                    short* __restrict__ wfh,
                                                    short* __restrict__ wfl) {
  const int e = blockIdx.x * 256 + threadIdx.x;
  if (e >= WFSZ) return;
  const int j = e & 7, lane = (e >> 3) & 63, ks = (e >> 9) & 1, mtkt = e >> 10;
  const int kt = mtkt / MTILES, mt = mtkt - kt * MTILES;
  const int o = mt * 16 + (lane & 15);
  const int k = kt * KT + ks * 32 + (lane >> 4) * 8 + j;
  const float w = (o < D_OUT && k < D_IN) ? W[o * D_IN + k] : 0.f;
  __bf16 h = (__bf16)w;
  float hf = (float)h;
  __bf16 l = (__bf16)(w - hf);
  wfh[e] = __builtin_bit_cast(short, h);
  wfl[e] = __builtin_bit_cast(short, l);
}

// ---------- QR (LAPACK sgeqrf convention), rcp-based, wave-private ----------
__device__ __forceinline__ void qr_and_store(const f32x4* acc, float* stg,
                                             float* dst, int lane, int col,
                                             int quad) {
  if (col < QD) {
    #pragma unroll
    for (int mt = 0; mt < MTILES; ++mt)
      #pragma unroll
      for (int rr = 0; rr < 4; ++rr) {
        const int o = mt * 16 + quad * 4 + rr;
        if (o < D_OUT) stg[o * QD + col] = acc[mt][rr];
      }
  }
  const int r = lane;
  float a0[QD], a1[QD];
  #pragma unroll
  for (int q = 0; q < QD; ++q) a0[q] = stg[r * QD + q];
  const bool has1 = (r + 64) < D_OUT;
  #pragma unroll
  for (int q = 0; q < QD; ++q) a1[q] = has1 ? stg[(r + 64) * QD + q] : 0.f;

  float v0[QD], v1[QD], tau[QD];
  #pragma unroll
  for (int j = 0; j < QD; ++j) {
    float cj0  = (r >= j) ? a0[j] : 0.f;
    float part = cj0 * cj0 + a1[j] * a1[j];
    float sig  = wsum64(part);
    float alpha = lane_bcast(a0[j], j);
    float nrm  = __builtin_amdgcn_sqrtf(sig);
    float aab  = fabsf(alpha);
    float rn   = __builtin_amdgcn_rcpf(nrm);
    float rd   = __builtin_amdgcn_rcpf(aab + nrm);
    float sgn  = (alpha >= 0.f) ? 1.f : -1.f;
    float tj   = (sig > 0.f) ? (1.f + aab * rn) : 0.f;
    float inv  = (sig > 0.f) ? sgn * rd : 0.f;      // 1/(alpha - beta)
    tau[j] = tj;
    v0[j]  = (r == j) ? 1.f : ((r > j) ? a0[j] * inv : 0.f);
    v1[j]  = a1[j] * inv;
    #pragma unroll
    for (int k = j + 1; k < QD; ++k) {
      float p = v0[j] * a0[k] + v1[j] * a1[k];
      float s = wsum64(p) * tj;
      a0[k] -= s * v0[j];
      a1[k] -= s * v1[j];
    }
  }
  float q0[QD], q1[QD];
  #pragma unroll
  for (int c = 0; c < QD; ++c) { q0[c] = (r == c) ? 1.f : 0.f; q1[c] = 0.f; }
  #pragma unroll
  for (int j = QD - 1; j >= 0; --j) {
    #pragma unroll
    for (int c = j; c < QD; ++c) {
      float p = v0[j] * q0[c] + v1[j] * q1[c];
      float s = wsum64(p) * tau[j];
      q0[c] -= s * v0[j];
      q1[c] -= s * v1[j];
    }
  }
  #pragma unroll
  for (int c = 0; c < QD; ++c) stg[r * QD + c] = q0[c];
  if (has1) {
    #pragma unroll
    for (int c = 0; c < QD; ++c) stg[(r + 64) * QD + c] = q1[c];
  }
  const float4* src = (const float4*)stg;
  float4* d4 = (float4*)dst;
  #pragma unroll
  for (int u = r; u < (D_OUT * QD) / 4; u += 64) d4[u] = src[u];
}

// ---------- fused: Y = W@X[b] (MFMA, W half-tiles via global_load_lds) + QR ----
__global__ __launch_bounds__(256, 3) void fused_kernel(const float* __restrict__ X,
                                                       const short* __restrict__ wfh,
                                                       const short* __restrict__ wfl,
                                                       float* __restrict__ out) {
  __shared__ __align__(16) float xstg[NW * 2 * XB];   // 20736 B wave-private X / QR stg
  __shared__ __align__(16) short wtile[2 * WHALF];    // 28672 B W half-tile double-buffer
  const int tid  = threadIdx.x;
  const int lane = tid & 63;
  const int wv   = __builtin_amdgcn_readfirstlane(tid >> 6);
  const long b0  = (long)blockIdx.x * (NW * 2) + wv * 2;
  float* xs = xstg + wv * (2 * XB);
  const int col = lane & 15, quad = lane >> 4;

  f32x4 acc0[MTILES], acc1[MTILES];
  #pragma unroll
  for (int t = 0; t < MTILES; ++t) {
    acc0[t] = (f32x4){0.f, 0.f, 0.f, 0.f};
    acc1[t] = (f32x4){0.f, 0.f, 0.f, 0.f};
  }

  // W half-tile async load: wave wv covers chunks {wv, wv+4, wv+8, wv+12}<14.
  // chunk c<7: hi plane mt=c ; c>=7: lo plane mt=c-7. 3 or 4 loads per wave
  // (wave-uniform count) — per-wave vmcnt waits below remain exact.
  auto wissue = [&](int kt, int ks, int half) {
    #pragma unroll
    for (int i = 0; i < 4; ++i) {
      const int c = wv + 4 * i;
      if (c < 14) {
        const short* pl = (c < 7) ? wfh : wfl;
        const int m = (c < 7) ? c : c - 7;
        gload_lds16(pl + ((long)(kt * MTILES + m) * 2 + ks) * WCH + lane * 8,
                    &wtile[half * WHALF + c * WCH]);
      }
    }
  };

  // X register prefetch (2 batches, 160 float4 each -> 5 per lane)
  float4 pre[5];
  auto xpre = [&](int kt) {
    const int nk0 = kt * KT;
    const int vf4 = (nk0 + KT <= D_IN) ? 160 : ((D_IN - nk0) * QD) / 4;  // 160 | 40
    #pragma unroll
    for (int u = 0; u < 5; ++u) {
      const int idx = lane + u * 64;
      const int bsel = idx >= 160 ? 1 : 0;
      const int within = idx - bsel * 160;
      float4 v = {0.f, 0.f, 0.f, 0.f};
      if (within < vf4)
        v = *(const float4*)(X + (b0 + bsel) * (long)(D_IN * QD) + nk0 * QD + within * 4);
      pre[u] = v;
    }
  };
  auto xcommit = [&]() {
    #pragma unroll
    for (int u = 0; u < 5; ++u) {
      const int idx = lane + u * 64;
      const int bsel = idx >= 160 ? 1 : 0;
      const int within = idx - bsel * 160;
      *(float4*)&xs[bsel * XB + within * 4] = pre[u];
    }
  };

  // one (kt,ks) half-tile of MFMA work for both batches; A-frags from LDS
  auto computeHalf = [&](int ks, int half) {
    bf16x8 b0h, b0l, b1h, b1l;
    #pragma unroll
    for (int m = 0; m < 8; ++m) {
      const int fo = (ks * 32 + quad * 8 + m) * QD + col;
      float x0 = xs[fo];
      float x1 = xs[XB + fo];
      __bf16 h0 = (__bf16)x0; float f0 = (float)h0; __bf16 g0 = (__bf16)(x0 - f0);
      __bf16 h1 = (__bf16)x1; float f1 = (float)h1; __bf16 g1 = (__bf16)(x1 - f1);
      b0h[m] = __builtin_bit_cast(short, h0); b0l[m] = __builtin_bit_cast(short, g0);
      b1h[m] = __builtin_bit_cast(short, h1); b1l[m] = __builtin_bit_cast(short, g1);
    }
    const short* wb = &wtile[half * WHALF];
    #pragma unroll
    for (int mt = 0; mt < MTILES; ++mt) {
      bf16x8 ah = *(const bf16x8*)(wb + mt * WCH + lane * 8);
      bf16x8 al = *(const bf16x8*)(wb + (7 + mt) * WCH + lane * 8);
      acc0[mt] = __builtin_amdgcn_mfma_f32_16x16x32_bf16(ah, b0h, acc0[mt], 0, 0, 0);
      acc0[mt] = __builtin_amdgcn_mfma_f32_16x16x32_bf16(al, b0h, acc0[mt], 0, 0, 0);
      acc0[mt] = __builtin_amdgcn_mfma_f32_16x16x32_bf16(ah, b0l, acc0[mt], 0, 0, 0);
      acc1[mt] = __builtin_amdgcn_mfma_f32_16x16x32_bf16(ah, b1h, acc1[mt], 0, 0, 0);
      acc1[mt] = __builtin_amdgcn_mfma_f32_16x16x32_bf16(al, b1h, acc1[mt], 0, 0, 0);
      acc1[mt] = __builtin_amdgcn_mfma_f32_16x16x32_bf16(ah, b1l, acc1[mt], 0, 0, 0);
    }
  };

  // ---- prologue: W(0,0) -> LDS (async), X(0) -> regs; order pinned so the
  // per-wave vmcnt queue is [W..., X5] and vmcnt(5) == "W done, X flying".
  wissue(0, 0, 0);
  __builtin_amdgcn_sched_barrier(0);
  xpre(0);
  asm volatile("s_waitcnt vmcnt(5)" ::: "memory");
  __builtin_amdgcn_s_barrier();
  __builtin_amdgcn_sched_barrier(0);

  #pragma unroll 1
  for (int kt = 0; kt < NKT; ++kt) {
    // ---- phase A: compute (kt,0) from half0; prefetch (kt,1) -> half1 ----
    xcommit();                           // compiler auto-waits X(kt) loads
    wissue(kt, 1, 1);
    computeHalf(0, 0);
    asm volatile("s_waitcnt vmcnt(0)" ::: "memory");   // W(kt,1) landed
    __builtin_amdgcn_s_barrier();
    __builtin_amdgcn_sched_barrier(0);
    // ---- phase B: compute (kt,1) from half1; prefetch (kt+1,0) -> half0,
    //      X(kt+1) -> regs (stays in flight across the barrier) ----
    if (kt + 1 < NKT) {
      wissue(kt + 1, 0, 0);
      __builtin_amdgcn_sched_barrier(0);
      xpre(kt + 1);
    }
    computeHalf(1, 1);
    if (kt + 1 < NKT) {
      asm volatile("s_waitcnt vmcnt(5)" ::: "memory"); // W done; X(kt+1) flying
      __builtin_amdgcn_s_barrier();
      __builtin_amdgcn_sched_barrier(0);
    }
  }

  // ---- fused QR + store (stg reuses the X region; wave-private, no barriers) ----
  qr_and_store(acc0, xs, out + b0 * (long)(D_OUT * QD), lane, col, quad);
  qr_and_store(acc1, xs, out + (b0 + 1) * (long)(D_OUT * QD), lane, col, quad);
}

extern "C" void kernel_launch(void* const* d_in, const int* in_sizes, int n_in,
                              void* d_out, int out_size, void* d_ws, size_t ws_size,
                              hipStream_t stream) {
  const float* X = (const float*)d_in[0];   // (8192, 400, 10) fp32
  const float* W = (const float*)d_in[1];   // (100, 400) fp32
  float* out = (float*)d_out;               // (8192, 100, 10) fp32
  short* wfh = (short*)d_ws;                // 50176 shorts
  short* wfl = wfh + WFSZ;                  // 50176 shorts
  hipLaunchKernelGGL(wprep_kernel, dim3((WFSZ + 255) / 256), dim3(256), 0, stream,
                     W, wfh, wfl);
  hipLaunchKernelGGL(fused_kernel, dim3(BATCHES / (NW * 2)), dim3(256), 0, stream,
                     X, wfh, wfl, out);
}